// Round 1
// 174.382 us; speedup vs baseline: 1.1219x; 1.1219x over previous
//
#include <hip/hip_runtime.h>
#include <cfloat>
#include <stdint.h>

// z: [32768, 32] fp32 rows; emb: [8192, 32] fp32 codes.
// Outputs (fp32, concat): quantized[1048576] | vq_loss | commit_loss | idx[32768]
//
// Strategy (R6): bf16 MFMA filter + exact fp32 re-check, fused sweep.
//  - one kernel: block = 128 rows x all 8192 codes (8 waves x 1024 codes).
//    pass 1: per-row max of approx dot (bf16 MFMA), combined via LDS ds_max.
//    pass 2: recompute (bitwise-identical d), emit candidates with
//            dot~ >= rowmax~ - 1e-4 (sound margin). Coarse per-frag test
//            (max_i d >= min_i th) skips the fine checks on ~all frags.
//  - finalize: exact fp32 chain on ~2-4 candidates/row (unchanged).
#define NROW   32768
#define KCODES 8192
#define CDIM   32
#define OUT_Q    0
#define OUT_LOSS 1048576
#define OUT_IDX  1048578
#define HALF_EPS 1e-4f
#define MAXCAND  32

typedef short bf8_t __attribute__((ext_vector_type(8)));   // 8 bf16 (4 VGPRs)
typedef float f32x4 __attribute__((ext_vector_type(4)));

__device__ __forceinline__ unsigned short f2bf(float f) {  // RNE float->bf16
  unsigned int u = __float_as_uint(f);
  return (unsigned short)((u + 0x7FFFu + ((u >> 16) & 1u)) >> 16);
}
// Order-preserving float<->uint transform (for atomicMax on signed floats).
__device__ __forceinline__ unsigned int xf(float f) {
  unsigned int u = __float_as_uint(f);
  return u ^ (unsigned int)(((int)u >> 31) | 0x80000000);
}
__device__ __forceinline__ float unxf(unsigned int k) {
  unsigned int u = (k & 0x80000000u) ? (k ^ 0x80000000u) : ~k;
  return __uint_as_float(u);
}

// ---------------------------------------------------------------------------
// Prep: z/emb -> bf16 copies; enorm (bit-identical chain); init ccnt/losses.
// grid 256x128 = 32768 threads.
// ---------------------------------------------------------------------------
__global__ __launch_bounds__(128) void vq_prep(
    const float* __restrict__ z, const float* __restrict__ emb,
    unsigned short* __restrict__ zh, unsigned short* __restrict__ eh,
    float* __restrict__ enorm, int* __restrict__ ccnt,
    float* __restrict__ out) {
  const int t = blockIdx.x * 128 + threadIdx.x;  // 0..32767
  {
    const float4* z4 = (const float4*)(z + (size_t)t * CDIM);
    unsigned int w[16];
#pragma unroll
    for (int j = 0; j < 8; ++j) {
      float4 v = z4[j];
      w[2 * j]     = (unsigned int)f2bf(v.x) | ((unsigned int)f2bf(v.y) << 16);
      w[2 * j + 1] = (unsigned int)f2bf(v.z) | ((unsigned int)f2bf(v.w) << 16);
    }
    uint4* o = (uint4*)(zh + (size_t)t * CDIM);
#pragma unroll
    for (int j = 0; j < 4; ++j)
      o[j] = make_uint4(w[4 * j], w[4 * j + 1], w[4 * j + 2], w[4 * j + 3]);
  }
  if (t < KCODES) {
    const float4* e4 = (const float4*)(emb + (size_t)t * CDIM);
    float s = 0.f;
    unsigned int w[16];
#pragma unroll
    for (int j = 0; j < 8; ++j) {
      float4 v = e4[j];
      s += v.x * v.x + v.y * v.y + v.z * v.z + v.w * v.w;  // exact enorm chain
      w[2 * j]     = (unsigned int)f2bf(v.x) | ((unsigned int)f2bf(v.y) << 16);
      w[2 * j + 1] = (unsigned int)f2bf(v.z) | ((unsigned int)f2bf(v.w) << 16);
    }
    enorm[t] = s;
    uint4* o = (uint4*)(eh + (size_t)t * CDIM);
#pragma unroll
    for (int j = 0; j < 4; ++j)
      o[j] = make_uint4(w[4 * j], w[4 * j + 1], w[4 * j + 2], w[4 * j + 3]);
  }
  ccnt[t] = 0;
  if (t < 2) out[OUT_LOSS + t] = 0.f;
}

// ---------------------------------------------------------------------------
// Fused sweep: block = 128 rows x ALL 8192 codes. 512 threads = 8 waves;
// wave w covers codes [w*1024, w*1024+1024) = 64 tiles of 16.
// A-frag f: A[m=lane&15][k=quad*8+j] = zh[rbase+f*16+m][k]   (8 frags)
// B-frag:   B[k][n=lane&15] = eh[code][k]
// C/D:      lane holds D[row=quad*4+i][col=lane&15], i=0..3.
//  pass 1: running max in regs -> ds_max flush -> LDS col-reduce -> rowmax.
//  pass 2: bitwise-identical recompute; candidates where d >= rowmax-eps.
// grid = 256 blocks (1/CU, 2 waves/SIMD).
// ---------------------------------------------------------------------------
__global__ __launch_bounds__(512, 2) void vq_sweep(
    const unsigned short* __restrict__ zh, const unsigned short* __restrict__ eh,
    int* __restrict__ ccnt, int* __restrict__ cand) {
  __shared__ unsigned int smax[128][16];  // [row][col] partial maxes (xf)
  __shared__ unsigned int rowmax[128];    // per-row max (xf)
  const int wid = threadIdx.x >> 6, lane = threadIdx.x & 63;
  const int quad = lane >> 4, col = lane & 15;
  const int rbase = blockIdx.x * 128;
  const int kbase = wid * 1024;

  for (int i = threadIdx.x; i < 128 * 16; i += 512)
    ((unsigned int*)smax)[i] = 0u;  // xf-space -inf

  bf8_t a[8];
#pragma unroll
  for (int f = 0; f < 8; ++f)
    a[f] = *(const bf8_t*)(zh + (size_t)(rbase + f * 16 + col) * CDIM + quad * 8);

  float mx[8][4];
#pragma unroll
  for (int f = 0; f < 8; ++f)
#pragma unroll
    for (int i = 0; i < 4; ++i) mx[f][i] = -FLT_MAX;

  const bf8_t* ep = (const bf8_t*)(eh + ((size_t)kbase + col) * CDIM + quad * 8);
  const f32x4 zero = {0.f, 0.f, 0.f, 0.f};
  __syncthreads();  // smax init visible before any ds_max

  // ---- pass 1: per-row max ----
#pragma unroll 2
  for (int tt = 0; tt < 64; tt += 4) {
    bf8_t b0 = ep[(size_t)(tt + 0) * 64];  // +16 codes * 64B per tile
    bf8_t b1 = ep[(size_t)(tt + 1) * 64];
    bf8_t b2 = ep[(size_t)(tt + 2) * 64];
    bf8_t b3 = ep[(size_t)(tt + 3) * 64];
#pragma unroll
    for (int f = 0; f < 8; ++f) {
      f32x4 d0 = __builtin_amdgcn_mfma_f32_16x16x32_bf16(a[f], b0, zero, 0, 0, 0);
      f32x4 d1 = __builtin_amdgcn_mfma_f32_16x16x32_bf16(a[f], b1, zero, 0, 0, 0);
      f32x4 d2 = __builtin_amdgcn_mfma_f32_16x16x32_bf16(a[f], b2, zero, 0, 0, 0);
      f32x4 d3 = __builtin_amdgcn_mfma_f32_16x16x32_bf16(a[f], b3, zero, 0, 0, 0);
#pragma unroll
      for (int i = 0; i < 4; ++i)  // 4-deep chain -> 2x v_max3_f32
        mx[f][i] = fmaxf(fmaxf(fmaxf(fmaxf(d0[i], d1[i]), d2[i]), d3[i]), mx[f][i]);
    }
  }
#pragma unroll
  for (int f = 0; f < 8; ++f)
#pragma unroll
    for (int i = 0; i < 4; ++i)
      atomicMax(&smax[f * 16 + quad * 4 + i][col], xf(mx[f][i]));
  __syncthreads();
  if (threadIdx.x < 128) {  // reduce 16 col-partials per row
    unsigned int m = 0u;
#pragma unroll
    for (int c = 0; c < 16; ++c) {
      unsigned int v = smax[threadIdx.x][c];
      if (v > m) m = v;
    }
    rowmax[threadIdx.x] = m;
  }
  __syncthreads();

  float th[8][4], thmin[8];
#pragma unroll
  for (int f = 0; f < 8; ++f) {
#pragma unroll
    for (int i = 0; i < 4; ++i)
      th[f][i] = unxf(rowmax[f * 16 + quad * 4 + i]) - HALF_EPS;
    thmin[f] = fminf(fminf(th[f][0], th[f][1]), fminf(th[f][2], th[f][3]));
  }

  // ---- pass 2: candidate emission (d bitwise identical to pass 1) ----
#define CHECK_TILE(dj, j)                                                    \
  {                                                                          \
    float md = fmaxf(fmaxf(dj[0], dj[1]), fmaxf(dj[2], dj[3]));              \
    if (md >= thmin[f]) {  /* coarse: no false negatives */                  \
      const int code = code0 + (j) * 16;                                     \
      _Pragma("unroll") for (int i = 0; i < 4; ++i) {                        \
        if (dj[i] >= th[f][i]) {                                             \
          int r = rbase + f * 16 + quad * 4 + i;                             \
          int s = atomicAdd(&ccnt[r], 1);                                    \
          if (s < MAXCAND) cand[(size_t)r * MAXCAND + s] = code;             \
        }                                                                    \
      }                                                                      \
    }                                                                        \
  }

  for (int tt = 0; tt < 64; tt += 4) {
    bf8_t b0 = ep[(size_t)(tt + 0) * 64];
    bf8_t b1 = ep[(size_t)(tt + 1) * 64];
    bf8_t b2 = ep[(size_t)(tt + 2) * 64];
    bf8_t b3 = ep[(size_t)(tt + 3) * 64];
    const int code0 = kbase + tt * 16 + col;
#pragma unroll
    for (int f = 0; f < 8; ++f) {
      f32x4 d0 = __builtin_amdgcn_mfma_f32_16x16x32_bf16(a[f], b0, zero, 0, 0, 0);
      f32x4 d1 = __builtin_amdgcn_mfma_f32_16x16x32_bf16(a[f], b1, zero, 0, 0, 0);
      f32x4 d2 = __builtin_amdgcn_mfma_f32_16x16x32_bf16(a[f], b2, zero, 0, 0, 0);
      f32x4 d3 = __builtin_amdgcn_mfma_f32_16x16x32_bf16(a[f], b3, zero, 0, 0, 0);
      CHECK_TILE(d0, 0)
      CHECK_TILE(d1, 1)
      CHECK_TILE(d2, 2)
      CHECK_TILE(d3, 3)
    }
  }
#undef CHECK_TILE
}

// ---------------------------------------------------------------------------
// Finalize: one thread per row. Exact fp32 re-eval of candidates with the
// bit-identical chain; overflow (>MAXCAND, never expected) falls back to a
// full exact scan. Then gather, idx, losses.  grid 256x128.
// ---------------------------------------------------------------------------
__global__ __launch_bounds__(128) void vq_final(
    const float* __restrict__ z, const float* __restrict__ emb,
    const float* __restrict__ enorm, const int* __restrict__ ccnt,
    const int* __restrict__ cand, float* __restrict__ out) {
  const int r = blockIdx.x * 128 + threadIdx.x;

  float zr[CDIM];
  const float4* z4 = (const float4*)(z + (size_t)r * CDIM);
#pragma unroll
  for (int j = 0; j < 8; ++j) {
    float4 v = z4[j];
    zr[4 * j + 0] = v.x; zr[4 * j + 1] = v.y;
    zr[4 * j + 2] = v.z; zr[4 * j + 3] = v.w;
  }
  float znorm = 0.f;
#pragma unroll
  for (int j = 0; j < CDIM; ++j) znorm = fmaf(zr[j], zr[j], znorm);

  const int n = ccnt[r];
  float best = FLT_MAX;
  int bidx = KCODES;
  if (n <= MAXCAND) {
    for (int j = 0; j < n; ++j) {
      int k = cand[(size_t)r * MAXCAND + j];
      const float* ek = emb + (size_t)k * CDIM;
      float dot = 0.f;
#pragma unroll
      for (int q = 0; q < CDIM; ++q) dot = fmaf(zr[q], ek[q], dot);
      float s = fmaf(-2.f, dot, znorm) + enorm[k];
      if (s < best || (s == best && k < bidx)) { best = s; bidx = k; }
    }
  } else {  // safety net: exact full scan, ascending k, strict <
    for (int k = 0; k < KCODES; ++k) {
      const float* ek = emb + (size_t)k * CDIM;
      float dot = 0.f;
#pragma unroll
      for (int q = 0; q < CDIM; ++q) dot = fmaf(zr[q], ek[q], dot);
      float s = fmaf(-2.f, dot, znorm) + enorm[k];
      if (s < best) { best = s; bidx = k; }
    }
  }

  const float4* q4 = (const float4*)(emb + (size_t)bidx * CDIM);
  float4* o4 = (float4*)(out + OUT_Q + (size_t)r * CDIM);
  float lsum = 0.f;
#pragma unroll
  for (int j = 0; j < 8; ++j) {
    float4 q = q4[j];
    float dx = zr[4 * j + 0] - q.x, dy = zr[4 * j + 1] - q.y;
    float dz = zr[4 * j + 2] - q.z, dw = zr[4 * j + 3] - q.w;
    lsum += dx * dx + dy * dy + dz * dz + dw * dw;
    o4[j] = q;
  }
  out[OUT_IDX + r] = (float)bidx;

#pragma unroll
  for (int off = 32; off > 0; off >>= 1) lsum += __shfl_down(lsum, off, 64);
  if ((threadIdx.x & 63) == 0) {
    float v = lsum * (1.0f / (float)(NROW * CDIM));
    atomicAdd(out + OUT_LOSS + 0, v);
    atomicAdd(out + OUT_LOSS + 1, v);
  }
}

// ---------------------------------------------------------------------------
extern "C" void kernel_launch(void* const* d_in, const int* in_sizes, int n_in,
                              void* d_out, int out_size, void* d_ws,
                              size_t ws_size, hipStream_t stream) {
  const float* z = (const float*)d_in[0];
  const float* emb = (const float*)d_in[1];
  float* out = (float*)d_out;

  // ws: enorm 32KB | zh 2MB | eh 512KB | ccnt 128KB | cand 4MB
  float* enorm = (float*)d_ws;
  unsigned short* zh = (unsigned short*)(enorm + KCODES);
  unsigned short* eh = zh + (size_t)NROW * CDIM;
  int* ccnt = (int*)(eh + (size_t)KCODES * CDIM);
  int* cand = ccnt + NROW;

  vq_prep<<<NROW / 128, 128, 0, stream>>>(z, emb, zh, eh, enorm, ccnt, out);
  vq_sweep<<<NROW / 128, 512, 0, stream>>>(zh, eh, ccnt, cand);
  vq_final<<<NROW / 128, 128, 0, stream>>>(z, emb, enorm, ccnt, cand, out);
}

// Round 2
// 156.929 us; speedup vs baseline: 1.2466x; 1.1112x over previous
//
#include <hip/hip_runtime.h>
#include <cfloat>
#include <stdint.h>

// z: [32768, 32] fp32 rows; emb: [8192, 32] fp32 codes.
// Outputs (fp32, concat): quantized[1048576] | vq_loss | commit_loss | idx[32768]
//
// Strategy (R7): bf16 MFMA filter + exact fp32 re-check, fused sweep.
//  R6->R7: occupancy fix. Block still = 128 rows x ALL 8192 codes, but with
//  16 waves (1024 thr) x 512 codes each; __launch_bounds__(1024,4) keeps
//  VGPR <= 128 so 4 waves/SIMD are resident (was 2). Loop body identical.
#define NROW   32768
#define KCODES 8192
#define CDIM   32
#define OUT_Q    0
#define OUT_LOSS 1048576
#define OUT_IDX  1048578
#define HALF_EPS 1e-4f
#define MAXCAND  32

typedef short bf8_t __attribute__((ext_vector_type(8)));   // 8 bf16 (4 VGPRs)
typedef float f32x4 __attribute__((ext_vector_type(4)));

__device__ __forceinline__ unsigned short f2bf(float f) {  // RNE float->bf16
  unsigned int u = __float_as_uint(f);
  return (unsigned short)((u + 0x7FFFu + ((u >> 16) & 1u)) >> 16);
}
// Order-preserving float<->uint transform (for atomicMax on signed floats).
__device__ __forceinline__ unsigned int xf(float f) {
  unsigned int u = __float_as_uint(f);
  return u ^ (unsigned int)(((int)u >> 31) | 0x80000000);
}
__device__ __forceinline__ float unxf(unsigned int k) {
  unsigned int u = (k & 0x80000000u) ? (k ^ 0x80000000u) : ~k;
  return __uint_as_float(u);
}

// ---------------------------------------------------------------------------
// Prep: z/emb -> bf16 copies; enorm (bit-identical chain); init ccnt/losses.
// grid 256x128 = 32768 threads.
// ---------------------------------------------------------------------------
__global__ __launch_bounds__(128) void vq_prep(
    const float* __restrict__ z, const float* __restrict__ emb,
    unsigned short* __restrict__ zh, unsigned short* __restrict__ eh,
    float* __restrict__ enorm, int* __restrict__ ccnt,
    float* __restrict__ out) {
  const int t = blockIdx.x * 128 + threadIdx.x;  // 0..32767
  {
    const float4* z4 = (const float4*)(z + (size_t)t * CDIM);
    unsigned int w[16];
#pragma unroll
    for (int j = 0; j < 8; ++j) {
      float4 v = z4[j];
      w[2 * j]     = (unsigned int)f2bf(v.x) | ((unsigned int)f2bf(v.y) << 16);
      w[2 * j + 1] = (unsigned int)f2bf(v.z) | ((unsigned int)f2bf(v.w) << 16);
    }
    uint4* o = (uint4*)(zh + (size_t)t * CDIM);
#pragma unroll
    for (int j = 0; j < 4; ++j)
      o[j] = make_uint4(w[4 * j], w[4 * j + 1], w[4 * j + 2], w[4 * j + 3]);
  }
  if (t < KCODES) {
    const float4* e4 = (const float4*)(emb + (size_t)t * CDIM);
    float s = 0.f;
    unsigned int w[16];
#pragma unroll
    for (int j = 0; j < 8; ++j) {
      float4 v = e4[j];
      s += v.x * v.x + v.y * v.y + v.z * v.z + v.w * v.w;  // exact enorm chain
      w[2 * j]     = (unsigned int)f2bf(v.x) | ((unsigned int)f2bf(v.y) << 16);
      w[2 * j + 1] = (unsigned int)f2bf(v.z) | ((unsigned int)f2bf(v.w) << 16);
    }
    enorm[t] = s;
    uint4* o = (uint4*)(eh + (size_t)t * CDIM);
#pragma unroll
    for (int j = 0; j < 4; ++j)
      o[j] = make_uint4(w[4 * j], w[4 * j + 1], w[4 * j + 2], w[4 * j + 3]);
  }
  ccnt[t] = 0;
  if (t < 2) out[OUT_LOSS + t] = 0.f;
}

// ---------------------------------------------------------------------------
// Fused sweep: block = 128 rows x ALL 8192 codes. 1024 threads = 16 waves;
// wave w covers codes [w*512, w*512+512) = 32 tiles of 16.
// A-frag f: A[m=lane&15][k=quad*8+j] = zh[rbase+f*16+m][k]   (8 frags)
// B-frag:   B[k][n=lane&15] = eh[code][k]
// C/D:      lane holds D[row=quad*4+i][col=lane&15], i=0..3.
//  pass 1: running max in regs -> ds_max flush -> LDS col-reduce -> rowmax.
//  pass 2: bitwise-identical recompute; candidates where d >= rowmax-eps.
// grid = 256 blocks (1/CU, 4 waves/SIMD).
// ---------------------------------------------------------------------------
__global__ __launch_bounds__(1024, 4) void vq_sweep(
    const unsigned short* __restrict__ zh, const unsigned short* __restrict__ eh,
    int* __restrict__ ccnt, int* __restrict__ cand) {
  __shared__ unsigned int smax[128][16];  // [row][col] partial maxes (xf)
  __shared__ unsigned int rowmax[128];    // per-row max (xf)
  const int wid = threadIdx.x >> 6, lane = threadIdx.x & 63;
  const int quad = lane >> 4, col = lane & 15;
  const int rbase = blockIdx.x * 128;
  const int kbase = wid * 512;

  for (int i = threadIdx.x; i < 128 * 16; i += 1024)
    ((unsigned int*)smax)[i] = 0u;  // xf-space -inf

  bf8_t a[8];
#pragma unroll
  for (int f = 0; f < 8; ++f)
    a[f] = *(const bf8_t*)(zh + (size_t)(rbase + f * 16 + col) * CDIM + quad * 8);

  float mx[8][4];
#pragma unroll
  for (int f = 0; f < 8; ++f)
#pragma unroll
    for (int i = 0; i < 4; ++i) mx[f][i] = -FLT_MAX;

  const bf8_t* ep = (const bf8_t*)(eh + ((size_t)kbase + col) * CDIM + quad * 8);
  const f32x4 zero = {0.f, 0.f, 0.f, 0.f};
  __syncthreads();  // smax init visible before any ds_max

  // ---- pass 1: per-row max ----
#pragma unroll 2
  for (int tt = 0; tt < 32; tt += 4) {
    bf8_t b0 = ep[(size_t)(tt + 0) * 64];  // +16 codes * 64B per tile
    bf8_t b1 = ep[(size_t)(tt + 1) * 64];
    bf8_t b2 = ep[(size_t)(tt + 2) * 64];
    bf8_t b3 = ep[(size_t)(tt + 3) * 64];
#pragma unroll
    for (int f = 0; f < 8; ++f) {
      f32x4 d0 = __builtin_amdgcn_mfma_f32_16x16x32_bf16(a[f], b0, zero, 0, 0, 0);
      f32x4 d1 = __builtin_amdgcn_mfma_f32_16x16x32_bf16(a[f], b1, zero, 0, 0, 0);
      f32x4 d2 = __builtin_amdgcn_mfma_f32_16x16x32_bf16(a[f], b2, zero, 0, 0, 0);
      f32x4 d3 = __builtin_amdgcn_mfma_f32_16x16x32_bf16(a[f], b3, zero, 0, 0, 0);
#pragma unroll
      for (int i = 0; i < 4; ++i)  // 4-deep chain -> 2x v_max3_f32
        mx[f][i] = fmaxf(fmaxf(fmaxf(fmaxf(d0[i], d1[i]), d2[i]), d3[i]), mx[f][i]);
    }
  }
#pragma unroll
  for (int f = 0; f < 8; ++f)
#pragma unroll
    for (int i = 0; i < 4; ++i)
      atomicMax(&smax[f * 16 + quad * 4 + i][col], xf(mx[f][i]));
  __syncthreads();
  if (threadIdx.x < 128) {  // reduce 16 col-partials per row
    unsigned int m = 0u;
#pragma unroll
    for (int c = 0; c < 16; ++c) {
      unsigned int v = smax[threadIdx.x][c];
      if (v > m) m = v;
    }
    rowmax[threadIdx.x] = m;
  }
  __syncthreads();

  float th[8][4], thmin[8];
#pragma unroll
  for (int f = 0; f < 8; ++f) {
#pragma unroll
    for (int i = 0; i < 4; ++i)
      th[f][i] = unxf(rowmax[f * 16 + quad * 4 + i]) - HALF_EPS;
    thmin[f] = fminf(fminf(th[f][0], th[f][1]), fminf(th[f][2], th[f][3]));
  }

  // ---- pass 2: candidate emission (d bitwise identical to pass 1) ----
#define CHECK_TILE(dj, j)                                                    \
  {                                                                          \
    float md = fmaxf(fmaxf(dj[0], dj[1]), fmaxf(dj[2], dj[3]));              \
    if (md >= thmin[f]) {  /* coarse: no false negatives */                  \
      const int code = code0 + (j) * 16;                                     \
      _Pragma("unroll") for (int i = 0; i < 4; ++i) {                        \
        if (dj[i] >= th[f][i]) {                                             \
          int r = rbase + f * 16 + quad * 4 + i;                             \
          int s = atomicAdd(&ccnt[r], 1);                                    \
          if (s < MAXCAND) cand[(size_t)r * MAXCAND + s] = code;             \
        }                                                                    \
      }                                                                      \
    }                                                                        \
  }

  for (int tt = 0; tt < 32; tt += 4) {
    bf8_t b0 = ep[(size_t)(tt + 0) * 64];
    bf8_t b1 = ep[(size_t)(tt + 1) * 64];
    bf8_t b2 = ep[(size_t)(tt + 2) * 64];
    bf8_t b3 = ep[(size_t)(tt + 3) * 64];
    const int code0 = kbase + tt * 16 + col;
#pragma unroll
    for (int f = 0; f < 8; ++f) {
      f32x4 d0 = __builtin_amdgcn_mfma_f32_16x16x32_bf16(a[f], b0, zero, 0, 0, 0);
      f32x4 d1 = __builtin_amdgcn_mfma_f32_16x16x32_bf16(a[f], b1, zero, 0, 0, 0);
      f32x4 d2 = __builtin_amdgcn_mfma_f32_16x16x32_bf16(a[f], b2, zero, 0, 0, 0);
      f32x4 d3 = __builtin_amdgcn_mfma_f32_16x16x32_bf16(a[f], b3, zero, 0, 0, 0);
      CHECK_TILE(d0, 0)
      CHECK_TILE(d1, 1)
      CHECK_TILE(d2, 2)
      CHECK_TILE(d3, 3)
    }
  }
#undef CHECK_TILE
}

// ---------------------------------------------------------------------------
// Finalize: one thread per row. Exact fp32 re-eval of candidates with the
// bit-identical chain; overflow (>MAXCAND, never expected) falls back to a
// full exact scan. Then gather, idx, losses.  grid 256x128.
// ---------------------------------------------------------------------------
__global__ __launch_bounds__(128) void vq_final(
    const float* __restrict__ z, const float* __restrict__ emb,
    const float* __restrict__ enorm, const int* __restrict__ ccnt,
    const int* __restrict__ cand, float* __restrict__ out) {
  const int r = blockIdx.x * 128 + threadIdx.x;

  float zr[CDIM];
  const float4* z4 = (const float4*)(z + (size_t)r * CDIM);
#pragma unroll
  for (int j = 0; j < 8; ++j) {
    float4 v = z4[j];
    zr[4 * j + 0] = v.x; zr[4 * j + 1] = v.y;
    zr[4 * j + 2] = v.z; zr[4 * j + 3] = v.w;
  }
  float znorm = 0.f;
#pragma unroll
  for (int j = 0; j < CDIM; ++j) znorm = fmaf(zr[j], zr[j], znorm);

  const int n = ccnt[r];
  float best = FLT_MAX;
  int bidx = KCODES;
  if (n <= MAXCAND) {
    for (int j = 0; j < n; ++j) {
      int k = cand[(size_t)r * MAXCAND + j];
      const float* ek = emb + (size_t)k * CDIM;
      float dot = 0.f;
#pragma unroll
      for (int q = 0; q < CDIM; ++q) dot = fmaf(zr[q], ek[q], dot);
      float s = fmaf(-2.f, dot, znorm) + enorm[k];
      if (s < best || (s == best && k < bidx)) { best = s; bidx = k; }
    }
  } else {  // safety net: exact full scan, ascending k, strict <
    for (int k = 0; k < KCODES; ++k) {
      const float* ek = emb + (size_t)k * CDIM;
      float dot = 0.f;
#pragma unroll
      for (int q = 0; q < CDIM; ++q) dot = fmaf(zr[q], ek[q], dot);
      float s = fmaf(-2.f, dot, znorm) + enorm[k];
      if (s < best) { best = s; bidx = k; }
    }
  }

  const float4* q4 = (const float4*)(emb + (size_t)bidx * CDIM);
  float4* o4 = (float4*)(out + OUT_Q + (size_t)r * CDIM);
  float lsum = 0.f;
#pragma unroll
  for (int j = 0; j < 8; ++j) {
    float4 q = q4[j];
    float dx = zr[4 * j + 0] - q.x, dy = zr[4 * j + 1] - q.y;
    float dz = zr[4 * j + 2] - q.z, dw = zr[4 * j + 3] - q.w;
    lsum += dx * dx + dy * dy + dz * dz + dw * dw;
    o4[j] = q;
  }
  out[OUT_IDX + r] = (float)bidx;

#pragma unroll
  for (int off = 32; off > 0; off >>= 1) lsum += __shfl_down(lsum, off, 64);
  if ((threadIdx.x & 63) == 0) {
    float v = lsum * (1.0f / (float)(NROW * CDIM));
    atomicAdd(out + OUT_LOSS + 0, v);
    atomicAdd(out + OUT_LOSS + 1, v);
  }
}

// ---------------------------------------------------------------------------
extern "C" void kernel_launch(void* const* d_in, const int* in_sizes, int n_in,
                              void* d_out, int out_size, void* d_ws,
                              size_t ws_size, hipStream_t stream) {
  const float* z = (const float*)d_in[0];
  const float* emb = (const float*)d_in[1];
  float* out = (float*)d_out;

  // ws: enorm 32KB | zh 2MB | eh 512KB | ccnt 128KB | cand 4MB
  float* enorm = (float*)d_ws;
  unsigned short* zh = (unsigned short*)(enorm + KCODES);
  unsigned short* eh = zh + (size_t)NROW * CDIM;
  int* ccnt = (int*)(eh + (size_t)KCODES * CDIM);
  int* cand = ccnt + NROW;

  vq_prep<<<NROW / 128, 128, 0, stream>>>(z, emb, zh, eh, enorm, ccnt, out);
  vq_sweep<<<NROW / 128, 1024, 0, stream>>>(zh, eh, ccnt, cand);
  vq_final<<<NROW / 128, 128, 0, stream>>>(z, emb, enorm, ccnt, cand, out);
}